// Round 8
// baseline (229.848 us; speedup 1.0000x reference)
//
#include <hip/hip_runtime.h>
#include <math.h>

// Problem constants
#define N_TOK 16384
#define DDIM  2048
#define NE    64
#define TK    8
#define BT    32              // tokens per block tile
#define NBLK  (N_TOK / BT)    // 512 blocks
#define NCH   8               // chunks of 256 K-floats (1 KB per row)

// Scaling keeps fp16 split residues normal; logits scaled by 2^17, unscaled
// exactly in the epilogue.
#define XSCALE 64.0f
#define WSCALE 2048.0f
#define LUNSCALE (1.0f / 131072.0f)

// Output layout (flat concat, all fp32)
constexpr size_t OFF_TOP  = 0;
constexpr size_t OFF_SC   = (size_t)N_TOK * TK;
constexpr size_t OFF_IDX  = OFF_SC + (size_t)N_TOK * NE;
constexpr size_t OFF_HIST = OFF_IDX + (size_t)N_TOK * TK;
constexpr size_t OFF_ENT  = OFF_HIST + NE;

#define WLVL (NE * DDIM)                  // 131072 f16 per split level
// Workspace layout
#define HISTC_OFF (1u << 20)              // 512 x 64 int  (128 KB)
#define ENTP_OFF  (HISTC_OFF + (1u << 17))
#define CTR_OFF   (ENTP_OFF + NBLK * 4)

typedef _Float16 f16x8 __attribute__((ext_vector_type(8)));
typedef float    f32x4  __attribute__((ext_vector_type(4)));
typedef float    f32x16 __attribute__((ext_vector_type(16)));

typedef const __attribute__((address_space(1))) unsigned int gu32;
typedef       __attribute__((address_space(3))) unsigned int lu32;

// 2-level fp16 split: v = h + m + r, |r| <= 2^-22 |v|. v - (float)h is exact.
__device__ __forceinline__ void split2(float v, _Float16& h, _Float16& m) {
    h = (_Float16)v;
    m = (_Float16)(v - (float)h);
}

__device__ __forceinline__ unsigned short f16bits(_Float16 h) {
    union { _Float16 f; unsigned short u; } c; c.f = h; return c.u;
}

// ---------------------------------------------------------------------------
// Prep: w*2048 -> 2-level fp16, 32x32x16 B-fragment-linear layout:
// frag (s16 = k/16, nt = e/32) is 64 lanes x 8 f16; lane = (k/8 % 2)*32 + e%32,
// j = k%8.  offset = ((s16*2+nt)*64 + lane)*8 + j   (+ lev*WLVL)
// Also zeroes the last-block counter (runs before router on the stream).
// ---------------------------------------------------------------------------
__global__ __launch_bounds__(64)
void prep_w(const float* __restrict__ w, unsigned short* __restrict__ wre,
            unsigned int* __restrict__ ctr) {
    if (blockIdx.x == 0 && threadIdx.x == 0) *ctr = 0u;

    int gid = blockIdx.x * 64 + threadIdx.x;   // 16384 threads, 8 elems each
    int e  = gid >> 8;
    int kb = gid & 255;
    int k  = kb * 8;
    const float* wp = w + (size_t)e * DDIM + k;
    float4 f0 = *(const float4*)(wp);
    float4 f1 = *(const float4*)(wp + 4);
    float av[8] = {f0.x, f0.y, f0.z, f0.w, f1.x, f1.y, f1.z, f1.w};

    int s16 = kb >> 1;                 // k/16
    int hi  = kb & 1;                  // (k/8)%2
    int nt  = e >> 5;
    int lane = hi * 32 + (e & 31);
    size_t off = ((size_t)(s16 * 2 + nt) * 64 + lane) * 8;

    unsigned short hb[8], mb[8];
    #pragma unroll
    for (int j = 0; j < 8; ++j) {
        _Float16 h, m;
        split2(av[j] * WSCALE, h, m);
        hb[j] = f16bits(h); mb[j] = f16bits(m);
    }

    #pragma unroll
    for (int lev = 0; lev < 2; ++lev) {
        const unsigned short* src = lev ? mb : hb;
        uint4 v;
        v.x = (unsigned)src[0] | ((unsigned)src[1] << 16);
        v.y = (unsigned)src[2] | ((unsigned)src[3] << 16);
        v.z = (unsigned)src[4] | ((unsigned)src[5] << 16);
        v.w = (unsigned)src[6] | ((unsigned)src[7] << 16);
        *(uint4*)(wre + (size_t)lev * WLVL + off) = v;
    }
}

// ---------------------------------------------------------------------------
// Fused GEMM + epilogue + finalize. 512 blocks x 512 threads (8 waves),
// 2 blocks/CU.  Block = 32 tokens.
//
// A-staging: chunk = 256 K-floats -> each DMA op is ONE fully-contiguous
// 1 KB row segment (vs R7's 8 scattered 128B pieces): best-case request
// coalescing and DRAM row-buffer locality.  Wave wid stages rows wid*4..+3;
// per-row source granules pre-swizzled (lane ^ (row&7)) so the swizzled
// LDS read is ~4-way-conflict (1.58x, hidden).  Waves slice K WITHIN each
// chunk: wave wid owns granules [wid*8, wid*8+8) of every row.
//
// Finalize is folded in via the split-K last-block pattern: per-block
// hist/entropy partials to workspace, __threadfence + device atomicAdd;
// winner block reduces (int hist: exact any order; entropy: fixed tree ->
// deterministic).  Dispatches: 4+memset -> 2.
// ---------------------------------------------------------------------------
__global__ __launch_bounds__(512, 4)
void router_fused(const float* __restrict__ x,
                  const unsigned short* __restrict__ wre,
                  const float* __restrict__ bias,
                  float* __restrict__ out,
                  int* __restrict__ histc,
                  float* __restrict__ entp,
                  unsigned int* __restrict__ ctr)
{
    union SMem {
        float As[2][8192];            // [buf][row*256 + slot*4f], 64 KB
        struct {
            float pl[16][16][64];     // [w*2+nt][reg][lane] partials, 64 KB
            float sct[NE][BT + 1];    // scores [expert][token]
            float bsh[NE];
            int   hist[NE];
            float entw[2];
            int   lastflag;
            float red[256];
        } ep;                          // ~75.5 KB -> 2 blocks/CU
    };
    __shared__ SMem sm;

    const int tid  = threadIdx.x;
    const int lane = tid & 63;
    const int wid  = tid >> 6;      // wave 0..7
    const int t0b  = blockIdx.x * BT;
    const int row  = lane & 31;     // token row in A fragment
    const int hi   = lane >> 5;     // k-subgroup

    if (tid < NE) { sm.ep.bsh[tid] = bias[tid]; sm.ep.hist[tid] = 0; }

    const unsigned short* wl = wre + (size_t)lane * 8;

    f32x16 acc[2];
    #pragma unroll
    for (int i = 0; i < 16; ++i) { acc[0][i] = 0.f; acc[1][i] = 0.f; }

    // Stage chunk c: wave wid stages rows wid*4..wid*4+3, one contiguous
    // 1 KB DMA per row; source granule for dest slot l is l ^ (r&7).
    auto stage = [&](int c, int buf) {
        #pragma unroll
        for (int i = 0; i < 4; ++i) {
            const int r = wid * 4 + i;
            const float* g = x + (size_t)(t0b + r) * DDIM + c * 256
                               + ((lane ^ (r & 7)) << 2);
            __builtin_amdgcn_global_load_lds((gu32*)g,
                (lu32*)&sm.As[buf][r * 256], 16, 0, 0);
        }
    };
    // B frags for global 16-K step s16: [0]=bh nt0 [1]=bh nt1 [2]=bm nt0 [3]=bm nt1
    auto loadB = [&](int s16, f16x8 (&B)[4]) {
        #pragma unroll
        for (int f = 0; f < 4; ++f)
            B[f] = *(const f16x8*)(wl + (size_t)(f >> 1) * WLVL
                                      + ((size_t)(s16 * 2 + (f & 1)) << 9));
    };
    // Step s (0/1) of a chunk: wave wid reads granules g0 = wid*8+s*4+hi*2,
    // +1 of each row, at swizzled slot g ^ (row&7).
    auto computeStep = [&](const float4* As4, int s, const f16x8 (&B)[4]) {
        const int g0 = wid * 8 + s * 4 + hi * 2;
        float4 G0 = As4[(row << 6) + ( g0      ^ (row & 7))];
        float4 G1 = As4[(row << 6) + ((g0 + 1) ^ (row & 7))];
        float av[8] = {G0.x, G0.y, G0.z, G0.w, G1.x, G1.y, G1.z, G1.w};
        f16x8 ah, am;
        #pragma unroll
        for (int j = 0; j < 8; ++j) {
            _Float16 h, m;
            split2(av[j] * XSCALE, h, m);
            ah[j] = h; am[j] = m;
        }
        #pragma unroll
        for (int nt = 0; nt < 2; ++nt) {
            acc[nt] = __builtin_amdgcn_mfma_f32_32x32x16_f16(ah, B[nt],     acc[nt], 0, 0, 0);
            acc[nt] = __builtin_amdgcn_mfma_f32_32x32x16_f16(am, B[nt],     acc[nt], 0, 0, 0);
            acc[nt] = __builtin_amdgcn_mfma_f32_32x32x16_f16(ah, B[2 + nt], acc[nt], 0, 0, 0);
            acc[nt] = __builtin_amdgcn_mfma_f32_32x32x16_f16(am, B[2 + nt], acc[nt], 0, 0, 0);
        }
    };

    f16x8 Bb[2][4];                  // step parity ring
    stage(0, 0);
    loadB(wid * 2, Bb[0]);           // c=0, s=0: s16 = c*16 + wid*2 + s
    __syncthreads();                 // vmcnt(0) drain: chunk 0 resident

    #pragma unroll
    for (int c = 0; c < NCH; ++c) {
        const int buf = c & 1;
        if (c + 1 < NCH) stage(c + 1, buf ^ 1);   // issue next chunk DMA
        const float4* As4 = (const float4*)&sm.As[buf][0];
        loadB(c * 16 + wid * 2 + 1, Bb[1]);
        __builtin_amdgcn_sched_barrier(0);
        computeStep(As4, 0, Bb[0]);
        if (c + 1 < NCH) loadB((c + 1) * 16 + wid * 2, Bb[0]);
        __builtin_amdgcn_sched_barrier(0);
        computeStep(As4, 1, Bb[1]);
        __syncthreads();             // one drain/chunk: waits chunk c+1 DMA
    }

    // ---- epilogue (As dead; ep overlays it) ----
    // C/D: col(expert%32)=lane&31, row(token)=(reg&3)+8*(reg>>2)+4*(lane>>5).
    #pragma unroll
    for (int nt = 0; nt < 2; ++nt)
        #pragma unroll
        for (int r = 0; r < 16; ++r)
            sm.ep.pl[wid * 2 + nt][r][lane] = acc[nt][r];
    __syncthreads();

    // Combine 8 wave-partials (fixed order), sigmoid, score store (coalesced).
    {
        const int tok = tid >> 4;               // 0..31
        const int e0  = (tid & 15) * 4;         // 0..60
        const int nt  = e0 >> 5;
        const int r   = (tok & 3) | ((tok >> 3) << 2);
        const int ln  = ((tok >> 2) & 1) * 32 + (e0 & 31);
        f32x4 s4 = {0.f, 0.f, 0.f, 0.f};
        #pragma unroll
        for (int w = 0; w < 8; ++w)
            s4 += *(const f32x4*)&sm.ep.pl[w * 2 + nt][r][ln];
        float4 sv;
        sv.x = 1.0f / (1.0f + expf(-s4[0] * LUNSCALE));
        sv.y = 1.0f / (1.0f + expf(-s4[1] * LUNSCALE));
        sv.z = 1.0f / (1.0f + expf(-s4[2] * LUNSCALE));
        sv.w = 1.0f / (1.0f + expf(-s4[3] * LUNSCALE));
        sm.ep.sct[e0 + 0][tok] = sv.x;
        sm.ep.sct[e0 + 1][tok] = sv.y;
        sm.ep.sct[e0 + 2][tok] = sv.z;
        sm.ep.sct[e0 + 3][tok] = sv.w;
        *(float4*)&out[OFF_SC + (size_t)(t0b + tok) * NE + e0] = sv;
    }
    __syncthreads();

    // Top-8: waves 0-1; lane = expert-group x 16 tokens.
    float entv = 0.f;
    if (wid < 2) {
        const int tl = wid * 16 + (lane & 15);
        const int eg = lane >> 4;               // expert group of 16
        float v[16];
        #pragma unroll
        for (int i = 0; i < 16; ++i)
            v[i] = sm.ep.sct[eg * 16 + i][tl] + sm.ep.bsh[eg * 16 + i];

        float ch[TK]; int ci[TK]; float ssum = 0.f;
        #pragma unroll
        for (int p = 0; p < TK; ++p) {
            float bv = v[0]; int bi = 0;
            #pragma unroll
            for (int i = 1; i < 16; ++i) {      // strict '>': lowest idx on tie
                const bool sgt = v[i] > bv;
                bv = sgt ? v[i] : bv;
                bi = sgt ? i : bi;
            }
            int be = eg * 16 + bi;
            {   // combine groups: lane^16 (same token, other group)
                float ov = __shfl_xor(bv, 16);
                int   oe = __shfl_xor(be, 16);
                const bool tk = (ov > bv) || (ov == bv && oe < be);
                bv = tk ? ov : bv; be = tk ? oe : be;
            }
            {   // lane^32
                float ov = __shfl_xor(bv, 32);
                int   oe = __shfl_xor(be, 32);
                const bool tk = (ov > bv) || (ov == bv && oe < be);
                bv = tk ? ov : bv; be = tk ? oe : be;
            }
            #pragma unroll
            for (int i = 0; i < 16; ++i)        // static-index mask (rule #20)
                v[i] = (be == eg * 16 + i) ? -1e30f : v[i];
            const float sc = sm.ep.sct[be][tl]; // unbiased score
            ch[p] = sc; ci[p] = be; ssum += sc;
        }
        if (eg == 0) {
            const float inv = 1.0f / (ssum + 1e-20f);
            #pragma unroll
            for (int p = 0; p < TK; ++p) {
                atomicAdd(&sm.ep.hist[ci[p]], 1);
                const float pn = ch[p] * inv;   // ROUTE_SCALE == 1.0
                out[OFF_TOP + (size_t)(t0b + tl) * TK + p] = pn;
                out[OFF_IDX + (size_t)(t0b + tl) * TK + p] = (float)ci[p];
                entv += pn * logf(pn);
            }
        }
        entv += __shfl_down(entv, 8);
        entv += __shfl_down(entv, 4);
        entv += __shfl_down(entv, 2);
        entv += __shfl_down(entv, 1);
        if (lane == 0) sm.ep.entw[wid] = entv;
    }
    __syncthreads();

    // Per-block partials to workspace.
    if (tid == 0) entp[blockIdx.x] = sm.ep.entw[0] + sm.ep.entw[1];
    if (tid < NE) histc[blockIdx.x * NE + tid] = sm.ep.hist[tid];
    __syncthreads();                 // all waves' stores issued (+vmcnt drain)

    // Last-block-done election (device-scope).
    if (tid == 0) {
        __threadfence();             // publish this block's stores (L2 wb)
        unsigned old = atomicAdd(ctr, 1u);
        sm.ep.lastflag = (old == NBLK - 1) ? 1 : 0;
    }
    __syncthreads();

    if (sm.ep.lastflag) {
        if (tid == 0) __threadfence();   // acquire: invalidate stale L2
        __syncthreads();
        // Histogram: thread t sums expert e=t&63 over block part p=t>>6
        // (64 blocks each); int adds exact in any order.
        {
            const int e = tid & 63, p = tid >> 6;
            int s = 0;
            for (int b = p * 64; b < p * 64 + 64; ++b)
                s += histc[b * NE + e];
            sm.ep.pl[0][p][e] = (float)0;        // (unused slot; keep LDS warm)
            atomicAdd(&sm.ep.hist[e], s);        // hist was re-zeroed? no ->
        }
        __syncthreads();
        // NOTE: sm.ep.hist still holds THIS block's per-block hist; that
        // value is already included via histc. Correct: subtract nothing --
        // we must start from 0. Re-zero then redo the atomic accumulate.
        if (tid < NE) sm.ep.hist[tid] = 0;
        __syncthreads();
        {
            const int e = tid & 63, p = tid >> 6;
            int s = 0;
            for (int b = p * 64; b < p * 64 + 64; ++b)
                s += histc[b * NE + e];
            atomicAdd(&sm.ep.hist[e], s);
        }
        __syncthreads();
        if (tid < NE) out[OFF_HIST + tid] = (float)sm.ep.hist[tid];
        // Entropy: fixed binary tree over 512 partials (deterministic).
        if (tid < 256) sm.ep.red[tid] = entp[tid] + entp[tid + 256];
        __syncthreads();
        #pragma unroll
        for (int o = 128; o > 0; o >>= 1) {
            if (tid < o) sm.ep.red[tid] += sm.ep.red[tid + o];
            __syncthreads();
        }
        if (tid == 0) out[OFF_ENT] = -sm.ep.red[0] * (1.0f / (float)N_TOK);
    }
}

extern "C" void kernel_launch(void* const* d_in, const int* in_sizes, int n_in,
                              void* d_out, int out_size, void* d_ws, size_t ws_size,
                              hipStream_t stream) {
    const float* x    = (const float*)d_in[0];   // [16384, 2048]
    const float* w    = (const float*)d_in[1];   // [64, 2048]
    const float* bias = (const float*)d_in[2];   // [64]
    float* out = (float*)d_out;
    unsigned short* wre = (unsigned short*)d_ws;            // 512 KB (2 levels)
    int*          histc = (int*)  ((char*)d_ws + HISTC_OFF);
    float*        entp  = (float*)((char*)d_ws + ENTP_OFF);
    unsigned int* ctr   = (unsigned int*)((char*)d_ws + CTR_OFF);

    prep_w      <<<dim3(256),  dim3(64),  0, stream>>>(w, wre, ctr);
    router_fused<<<dim3(NBLK), dim3(512), 0, stream>>>(x, wre, bias, out,
                                                       histc, entp, ctr);
}

// Round 9
// 225.916 us; speedup vs baseline: 1.0174x; 1.0174x over previous
//
#include <hip/hip_runtime.h>
#include <math.h>

// Problem constants
#define N_TOK 16384
#define DDIM  2048
#define NE    64
#define TK    8
#define BT    32              // tokens per block tile
#define NBLK  (N_TOK / BT)    // 512 blocks
#define KSL   256             // K per wave slice (8 waves cover 2048)
#define CHK   64              // K-floats per chunk
#define NCHK  (KSL / CHK)     // 4 chunks per wave

// Scaling keeps fp16 split residues normal; logits scaled by 2^17, unscaled
// exactly in the epilogue.
#define XSCALE 64.0f
#define WSCALE 2048.0f
#define LUNSCALE (1.0f / 131072.0f)

// Output layout (flat concat, all fp32)
constexpr size_t OFF_TOP  = 0;
constexpr size_t OFF_SC   = (size_t)N_TOK * TK;
constexpr size_t OFF_IDX  = OFF_SC + (size_t)N_TOK * NE;
constexpr size_t OFF_HIST = OFF_IDX + (size_t)N_TOK * TK;
constexpr size_t OFF_ENT  = OFF_HIST + NE;

#define WLVL (NE * DDIM)                  // 131072 f16 per split level
// Workspace layout
#define HISTC_OFF (1u << 20)              // 512 x 64 int (128 KB), no atomics
#define ENTP_OFF  (HISTC_OFF + (1u << 17))

typedef _Float16 f16x8 __attribute__((ext_vector_type(8)));
typedef float    f32x4  __attribute__((ext_vector_type(4)));
typedef float    f32x16 __attribute__((ext_vector_type(16)));

typedef const __attribute__((address_space(1))) unsigned int gu32;
typedef       __attribute__((address_space(3))) unsigned int lu32;

// 2-level fp16 split: v = h + m + r, |r| <= 2^-22 |v|. v - (float)h is exact.
__device__ __forceinline__ void split2(float v, _Float16& h, _Float16& m) {
    h = (_Float16)v;
    m = (_Float16)(v - (float)h);
}

__device__ __forceinline__ unsigned short f16bits(_Float16 h) {
    union { _Float16 f; unsigned short u; } c; c.f = h; return c.u;
}

// ---------------------------------------------------------------------------
// Prep: w*2048 -> 2-level fp16, 32x32x16 B-fragment-linear layout:
// frag (s16 = k/16, nt = e/32) is 64 lanes x 8 f16; lane = (k/8 % 2)*32 + e%32,
// j = k%8.  offset = ((s16*2+nt)*64 + lane)*8 + j   (+ lev*WLVL)
// ---------------------------------------------------------------------------
__global__ __launch_bounds__(64)
void prep_w(const float* __restrict__ w, unsigned short* __restrict__ wre) {
    int gid = blockIdx.x * 64 + threadIdx.x;   // 16384 threads, 8 elems each
    int e  = gid >> 8;
    int kb = gid & 255;
    int k  = kb * 8;
    const float* wp = w + (size_t)e * DDIM + k;
    float4 f0 = *(const float4*)(wp);
    float4 f1 = *(const float4*)(wp + 4);
    float av[8] = {f0.x, f0.y, f0.z, f0.w, f1.x, f1.y, f1.z, f1.w};

    int s16 = kb >> 1;                 // k/16
    int hi  = kb & 1;                  // (k/8)%2
    int nt  = e >> 5;
    int lane = hi * 32 + (e & 31);
    size_t off = ((size_t)(s16 * 2 + nt) * 64 + lane) * 8;

    unsigned short hb[8], mb[8];
    #pragma unroll
    for (int j = 0; j < 8; ++j) {
        _Float16 h, m;
        split2(av[j] * WSCALE, h, m);
        hb[j] = f16bits(h); mb[j] = f16bits(m);
    }

    #pragma unroll
    for (int lev = 0; lev < 2; ++lev) {
        const unsigned short* src = lev ? mb : hb;
        uint4 v;
        v.x = (unsigned)src[0] | ((unsigned)src[1] << 16);
        v.y = (unsigned)src[2] | ((unsigned)src[3] << 16);
        v.z = (unsigned)src[4] | ((unsigned)src[5] << 16);
        v.w = (unsigned)src[6] | ((unsigned)src[7] << 16);
        *(uint4*)(wre + (size_t)lev * WLVL + off) = v;
    }
}

// ---------------------------------------------------------------------------
// Fused GEMM + epilogue, BARRIER-FREE main loop (T4 counted-vmcnt, first
// real implementation).  512 blocks x 512 threads (8 waves), 1 block/CU.
// Block = 32 tokens; wave wid owns K-slice [wid*256, wid*256+256) and its
// OWN LDS staging ring (2 x 8 KB).  All prior variants re-synced the whole
// block every chunk: __syncthreads' vmcnt(0) drain stops issue, drains the
// queue, and 512 blocks burst in lockstep (convoy; measured ~26% of the
// per-CU HBM fair share).  Here each wave free-runs:
//   iter c: DMA(c+1) 8 ops | loadB(c+1) 16 ops | s_waitcnt vmcnt(24) |
//           compute chunk c
// vmcnt(24) retires exactly the PREVIOUS chunk's 24 ops; one full chunk
// (~24 KB/wave incl. B) stays in flight at all times; never drains to 0
// until the last iter.  sched_barrier(0) fences pin the regions (rule #18).
// ---------------------------------------------------------------------------
__global__ __launch_bounds__(512, 2)
void router_fused(const float* __restrict__ x,
                  const unsigned short* __restrict__ wre,
                  const float* __restrict__ bias,
                  float* __restrict__ out,
                  int* __restrict__ histc,
                  float* __restrict__ entp)
{
    union SMem {
        float As[8][2][2048];         // [wid][buf][row*64 + slot*4f], 128 KB
        struct {                      // valid only after post-loop barrier
            float pl[16][16][64];     // [w*2+nt][reg][lane] partials, 64 KB
            float sct[NE][BT + 1];    // scores [expert][token]
            float bsh[NE];
            int   hist[NE];
            float entw[2];
        } ep;
    };
    __shared__ SMem sm;

    const int tid  = threadIdx.x;
    const int lane = tid & 63;
    const int wid  = tid >> 6;      // wave 0..7 = K-slice
    const int t0b  = blockIdx.x * BT;
    const int row  = lane & 31;     // token row in A fragment
    const int hi   = lane >> 5;     // k-subgroup

    const unsigned short* wl = wre + (size_t)lane * 8;
    // Staging: op o covers rows 4o..4o+3 (16 lanes x 16B each, one
    // contiguous 256B segment per row).  Source granule pre-swizzled
    // (g ^ (r&7)) so the swizzled LDS read is ~4-way conflict (rule #21:
    // linear dest + inverse-swz source + swz read).
    const int rl4 = lane >> 4;      // row-within-op 0..3
    const int g15 = lane & 15;      // dest granule slot

    f32x16 acc[2];
    #pragma unroll
    for (int i = 0; i < 16; ++i) { acc[0][i] = 0.f; acc[1][i] = 0.f; }

    auto stage = [&](int c, int buf) {
        #pragma unroll
        for (int o = 0; o < 8; ++o) {
            const int r = o * 4 + rl4;
            const float* g = x + (size_t)(t0b + r) * DDIM + wid * KSL
                               + c * CHK + ((g15 ^ (r & 7)) << 2);
            __builtin_amdgcn_global_load_lds((gu32*)g,
                (lu32*)&sm.As[wid][buf][o * 256], 16, 0, 0);
        }
    };
    // B frags for chunk c: 4 steps x {bh nt0, bh nt1, bm nt0, bm nt1}
    auto loadBchunk = [&](int c, f16x8 (&B)[16]) {
        #pragma unroll
        for (int s = 0; s < 4; ++s)
            #pragma unroll
            for (int f = 0; f < 4; ++f) {
                const int s16 = wid * 16 + c * 4 + s;
                B[s * 4 + f] = *(const f16x8*)(wl + (size_t)(f >> 1) * WLVL
                                  + ((size_t)(s16 * 2 + (f & 1)) << 9));
            }
    };
    auto computeChunk = [&](int buf, const f16x8 (&B)[16]) {
        #pragma unroll
        for (int s = 0; s < 4; ++s) {
            const int g0 = s * 4 + hi * 2;
            float4 G0 = *(const float4*)&sm.As[wid][buf]
                            [row * 64 + (( g0      ^ (row & 7)) << 2)];
            float4 G1 = *(const float4*)&sm.As[wid][buf]
                            [row * 64 + (((g0 + 1) ^ (row & 7)) << 2)];
            float av[8] = {G0.x, G0.y, G0.z, G0.w, G1.x, G1.y, G1.z, G1.w};
            f16x8 ah, am;
            #pragma unroll
            for (int j = 0; j < 8; ++j) {
                _Float16 h, m;
                split2(av[j] * XSCALE, h, m);
                ah[j] = h; am[j] = m;
            }
            #pragma unroll
            for (int nt = 0; nt < 2; ++nt) {
                acc[nt] = __builtin_amdgcn_mfma_f32_32x32x16_f16(ah, B[s*4 + nt],     acc[nt], 0, 0, 0);
                acc[nt] = __builtin_amdgcn_mfma_f32_32x32x16_f16(am, B[s*4 + nt],     acc[nt], 0, 0, 0);
                acc[nt] = __builtin_amdgcn_mfma_f32_32x32x16_f16(ah, B[s*4 + 2 + nt], acc[nt], 0, 0, 0);
                acc[nt] = __builtin_amdgcn_mfma_f32_32x32x16_f16(am, B[s*4 + 2 + nt], acc[nt], 0, 0, 0);
            }
        }
    };

    f16x8 Ba[16], Bb[16];             // chunk-deep B ring (static names)
    // Prologue: chunk 0 in flight.
    stage(0, 0);
    __builtin_amdgcn_sched_barrier(0);
    loadBchunk(0, Ba);
    __builtin_amdgcn_sched_barrier(0);

    auto iter = [&](int c, const f16x8 (&Bcur)[16], f16x8 (&Bnxt)[16],
                    bool last) {
        if (!last) {
            stage(c + 1, (c + 1) & 1);
            __builtin_amdgcn_sched_barrier(0);
            loadBchunk(c + 1, Bnxt);
            __builtin_amdgcn_sched_barrier(0);
            // retire chunk c's 24 ops; keep chunk c+1's 24 in flight
            asm volatile("s_waitcnt vmcnt(24)" ::: "memory");
        } else {
            asm volatile("s_waitcnt vmcnt(0)" ::: "memory");
        }
        __builtin_amdgcn_sched_barrier(0);
        computeChunk(c & 1, Bcur);
    };
    iter(0, Ba, Bb, false);
    iter(1, Bb, Ba, false);
    iter(2, Ba, Bb, false);
    iter(3, Bb, Ba, true);

    // ---- epilogue (first and only block-wide syncs) ----
    __syncthreads();                  // all waves done with As
    if (tid < NE) { sm.ep.bsh[tid] = bias[tid]; sm.ep.hist[tid] = 0; }
    // C/D: col(expert%32)=lane&31, row(token)=(reg&3)+8*(reg>>2)+4*(lane>>5).
    #pragma unroll
    for (int nt = 0; nt < 2; ++nt)
        #pragma unroll
        for (int r = 0; r < 16; ++r)
            sm.ep.pl[wid * 2 + nt][r][lane] = acc[nt][r];
    __syncthreads();

    // Combine 8 wave-partials (fixed order), sigmoid, score store (coalesced).
    {
        const int tok = tid >> 4;               // 0..31
        const int e0  = (tid & 15) * 4;         // 0..60
        const int nt  = e0 >> 5;
        const int r   = (tok & 3) | ((tok >> 3) << 2);
        const int ln  = ((tok >> 2) & 1) * 32 + (e0 & 31);
        f32x4 s4 = {0.f, 0.f, 0.f, 0.f};
        #pragma unroll
        for (int w = 0; w < 8; ++w)
            s4 += *(const f32x4*)&sm.ep.pl[w * 2 + nt][r][ln];
        float4 sv;
        sv.x = 1.0f / (1.0f + expf(-s4[0] * LUNSCALE));
        sv.y = 1.0f / (1.0f + expf(-s4[1] * LUNSCALE));
        sv.z = 1.0f / (1.0f + expf(-s4[2] * LUNSCALE));
        sv.w = 1.0f / (1.0f + expf(-s4[3] * LUNSCALE));
        sm.ep.sct[e0 + 0][tok] = sv.x;
        sm.ep.sct[e0 + 1][tok] = sv.y;
        sm.ep.sct[e0 + 2][tok] = sv.z;
        sm.ep.sct[e0 + 3][tok] = sv.w;
        *(float4*)&out[OFF_SC + (size_t)(t0b + tok) * NE + e0] = sv;
    }
    __syncthreads();

    // Top-8: waves 0-1; lane = expert-group x 16 tokens.
    float entv = 0.f;
    if (wid < 2) {
        const int tl = wid * 16 + (lane & 15);
        const int eg = lane >> 4;               // expert group of 16
        float v[16];
        #pragma unroll
        for (int i = 0; i < 16; ++i)
            v[i] = sm.ep.sct[eg * 16 + i][tl] + sm.ep.bsh[eg * 16 + i];

        float ch[TK]; int ci[TK]; float ssum = 0.f;
        #pragma unroll
        for (int p = 0; p < TK; ++p) {
            float bv = v[0]; int bi = 0;
            #pragma unroll
            for (int i = 1; i < 16; ++i) {      // strict '>': lowest idx on tie
                const bool sgt = v[i] > bv;
                bv = sgt ? v[i] : bv;
                bi = sgt ? i : bi;
            }
            int be = eg * 16 + bi;
            {   // combine groups: lane^16 (same token, other group)
                float ov = __shfl_xor(bv, 16);
                int   oe = __shfl_xor(be, 16);
                const bool tk = (ov > bv) || (ov == bv && oe < be);
                bv = tk ? ov : bv; be = tk ? oe : be;
            }
            {   // lane^32
                float ov = __shfl_xor(bv, 32);
                int   oe = __shfl_xor(be, 32);
                const bool tk = (ov > bv) || (ov == bv && oe < be);
                bv = tk ? ov : bv; be = tk ? oe : be;
            }
            #pragma unroll
            for (int i = 0; i < 16; ++i)        // static-index mask (rule #20)
                v[i] = (be == eg * 16 + i) ? -1e30f : v[i];
            const float sc = sm.ep.sct[be][tl]; // unbiased score
            ch[p] = sc; ci[p] = be; ssum += sc;
        }
        if (eg == 0) {
            const float inv = 1.0f / (ssum + 1e-20f);
            #pragma unroll
            for (int p = 0; p < TK; ++p) {
                atomicAdd(&sm.ep.hist[ci[p]], 1);
                const float pn = ch[p] * inv;   // ROUTE_SCALE == 1.0
                out[OFF_TOP + (size_t)(t0b + tl) * TK + p] = pn;
                out[OFF_IDX + (size_t)(t0b + tl) * TK + p] = (float)ci[p];
                entv += pn * logf(pn);
            }
        }
        entv += __shfl_down(entv, 8);
        entv += __shfl_down(entv, 4);
        entv += __shfl_down(entv, 2);
        entv += __shfl_down(entv, 1);
        if (lane == 0) sm.ep.entw[wid] = entv;
    }
    __syncthreads();

    // Per-block partials: plain coalesced stores, NO global atomics.
    if (tid == 0) entp[blockIdx.x] = sm.ep.entw[0] + sm.ep.entw[1];
    if (tid < NE) histc[blockIdx.x * NE + tid] = sm.ep.hist[tid];
}

// ---------------------------------------------------------------------------
// Finalize: reduce per-block histogram rows and entropy partials.
// ---------------------------------------------------------------------------
__global__ __launch_bounds__(256)
void finalize(const int* __restrict__ histc,
              const float* __restrict__ entp,
              float* __restrict__ out)
{
    __shared__ int   hred[4][NE];
    __shared__ float ered[256];
    const int tid = threadIdx.x;
    {
        const int e = tid & 63, p = tid >> 6;   // 4 partitions x 128 blocks
        int s = 0;
        for (int b = p * 128; b < p * 128 + 128; ++b)
            s += histc[b * NE + e];
        hred[p][e] = s;
    }
    float ev = 0.f;
    for (int i = tid; i < NBLK; i += 256) ev += entp[i];
    ered[tid] = ev;
    __syncthreads();
    if (tid < NE)
        out[OFF_HIST + tid] =
            (float)(hred[0][tid] + hred[1][tid] + hred[2][tid] + hred[3][tid]);
    #pragma unroll
    for (int o = 128; o > 0; o >>= 1) {
        if (tid < o) ered[tid] += ered[tid + o];
        __syncthreads();
    }
    if (tid == 0) out[OFF_ENT] = -ered[0] * (1.0f / (float)N_TOK);
}

extern "C" void kernel_launch(void* const* d_in, const int* in_sizes, int n_in,
                              void* d_out, int out_size, void* d_ws, size_t ws_size,
                              hipStream_t stream) {
    const float* x    = (const float*)d_in[0];   // [16384, 2048]
    const float* w    = (const float*)d_in[1];   // [64, 2048]
    const float* bias = (const float*)d_in[2];   // [64]
    float* out = (float*)d_out;
    unsigned short* wre = (unsigned short*)d_ws;            // 512 KB (2 levels)
    int*   histc = (int*)  ((char*)d_ws + HISTC_OFF);
    float* entp  = (float*)((char*)d_ws + ENTP_OFF);

    prep_w      <<<dim3(256),  dim3(64),  0, stream>>>(w, wre);
    router_fused<<<dim3(NBLK), dim3(512), 0, stream>>>(x, wre, bias, out,
                                                       histc, entp);
    finalize    <<<dim3(1),    dim3(256), 0, stream>>>(histc, entp, out);
}

// Round 10
// 211.021 us; speedup vs baseline: 1.0892x; 1.0706x over previous
//
#include <hip/hip_runtime.h>
#include <math.h>

// Problem constants
#define N_TOK 16384
#define DDIM  2048
#define NE    64
#define TK    8
#define BT    32              // tokens per block tile
#define NBLK  (N_TOK / BT)    // 512 blocks
#define KSL   256             // K per wave slice (8 slices cover 2048)
#define NCH   8               // chunks per wave slice (32 K each)

// Scaling keeps fp16 split residues normal; logits scaled by 2^17, unscaled
// exactly in the epilogue.
#define XSCALE 64.0f
#define WSCALE 2048.0f
#define LUNSCALE (1.0f / 131072.0f)

// Output layout (flat concat, all fp32)
constexpr size_t OFF_TOP  = 0;
constexpr size_t OFF_SC   = (size_t)N_TOK * TK;
constexpr size_t OFF_IDX  = OFF_SC + (size_t)N_TOK * NE;
constexpr size_t OFF_HIST = OFF_IDX + (size_t)N_TOK * TK;
constexpr size_t OFF_ENT  = OFF_HIST + NE;

#define WLVL (NE * DDIM)                  // 131072 f16 per split level
// Workspace layout
#define HISTC_OFF (1u << 20)              // 512 x 64 int (128 KB), no atomics
#define ENTP_OFF  (HISTC_OFF + (1u << 17))

typedef _Float16 f16x8 __attribute__((ext_vector_type(8)));
typedef float    f32x4  __attribute__((ext_vector_type(4)));
typedef float    f32x16 __attribute__((ext_vector_type(16)));

typedef const __attribute__((address_space(1))) unsigned int gu32;
typedef       __attribute__((address_space(3))) unsigned int lu32;

// 2-level fp16 split: v = h + m + r, |r| <= 2^-22 |v|. v - (float)h is exact.
__device__ __forceinline__ void split2(float v, _Float16& h, _Float16& m) {
    h = (_Float16)v;
    m = (_Float16)(v - (float)h);
}

__device__ __forceinline__ unsigned short f16bits(_Float16 h) {
    union { _Float16 f; unsigned short u; } c; c.f = h; return c.u;
}

// ---------------------------------------------------------------------------
// Prep: w*2048 -> 2-level fp16, 32x32x16 B-fragment-linear layout:
// frag (s16 = k/16, nt = e/32) is 64 lanes x 8 f16; lane = (k/8 % 2)*32 + e%32,
// j = k%8.  offset = ((s16*2+nt)*64 + lane)*8 + j   (+ lev*WLVL)
// ---------------------------------------------------------------------------
__global__ __launch_bounds__(64)
void prep_w(const float* __restrict__ w, unsigned short* __restrict__ wre) {
    int gid = blockIdx.x * 64 + threadIdx.x;   // 16384 threads, 8 elems each
    int e  = gid >> 8;
    int kb = gid & 255;
    int k  = kb * 8;
    const float* wp = w + (size_t)e * DDIM + k;
    float4 f0 = *(const float4*)(wp);
    float4 f1 = *(const float4*)(wp + 4);
    float av[8] = {f0.x, f0.y, f0.z, f0.w, f1.x, f1.y, f1.z, f1.w};

    int s16 = kb >> 1;                 // k/16
    int hi  = kb & 1;                  // (k/8)%2
    int nt  = e >> 5;
    int lane = hi * 32 + (e & 31);
    size_t off = ((size_t)(s16 * 2 + nt) * 64 + lane) * 8;

    unsigned short hb[8], mb[8];
    #pragma unroll
    for (int j = 0; j < 8; ++j) {
        _Float16 h, m;
        split2(av[j] * WSCALE, h, m);
        hb[j] = f16bits(h); mb[j] = f16bits(m);
    }

    #pragma unroll
    for (int lev = 0; lev < 2; ++lev) {
        const unsigned short* src = lev ? mb : hb;
        uint4 v;
        v.x = (unsigned)src[0] | ((unsigned)src[1] << 16);
        v.y = (unsigned)src[2] | ((unsigned)src[3] << 16);
        v.z = (unsigned)src[4] | ((unsigned)src[5] << 16);
        v.w = (unsigned)src[6] | ((unsigned)src[7] << 16);
        *(uint4*)(wre + (size_t)lev * WLVL + off) = v;
    }
}

// ---------------------------------------------------------------------------
// Fused GEMM + epilogue -- the empirically best structure (R6-proposal,
// 209 us total / ~60 us router): 512 blocks x 512 threads (8 waves),
// 2 blocks/CU.  Block = 32 tokens; wave w = K-slice [w*256, w*256+256).
// A-staging fully coalesced: stage op i covers 8 COMPLETE rows (lane l ->
// row 8i+(l>>3), granule (l&7)), source XOR-pre-swizzled (g ^= row&7) so
// the swizzled LDS read is ~4-way conflict (rule #21).  B: depth-1 register
// ring pinned with sched_barrier(0).  One barrier per chunk.
// Delta vs 209-run: histogram per-block plain stores (no global atomics,
// no memset dispatch); separate 1-block finalize.
// ---------------------------------------------------------------------------
__global__ __launch_bounds__(512, 4)
void router_fused(const float* __restrict__ x,
                  const unsigned short* __restrict__ wre,
                  const float* __restrict__ bias,
                  float* __restrict__ out,
                  int* __restrict__ histc,
                  float* __restrict__ entp)
{
    union SMem {
        float As[2][8192];            // [buf][wid*1024 + (row*8+g)*4f], 64 KB
        struct {
            float pl[16][16][64];     // [w*2+nt][reg][lane] partials, 64 KB
            float sct[NE][BT + 1];    // scores [expert][token]
            float bsh[NE];
            int   hist[NE];
            float entw[2];
        } ep;                          // ~74.5 KB -> 2 blocks/CU
    };
    __shared__ SMem sm;

    const int tid  = threadIdx.x;
    const int lane = tid & 63;
    const int wid  = tid >> 6;      // K-slice 0..7
    const int t0b  = blockIdx.x * BT;
    const int row  = lane & 31;     // token row in A fragment
    const int hi   = lane >> 5;     // k-subgroup

    if (tid < NE) { sm.ep.bsh[tid] = bias[tid]; sm.ep.hist[tid] = 0; }

    // Staging source: lane l covers row (l>>3) (+8 per op), granule
    // (l&7)^((l>>3)&7)  (XOR pre-swizzle; 128B segment per 8 lanes).
    const float* xrow = x + (size_t)(t0b + (lane >> 3)) * DDIM + wid * KSL
                          + (((lane & 7) ^ ((lane >> 3) & 7)) << 2);
    const unsigned short* wl = wre + (size_t)lane * 8;
    const int s16b = wid * (KSL / 16);  // global 16-K step base

    f32x16 acc[2];
    #pragma unroll
    for (int i = 0; i < 16; ++i) { acc[0][i] = 0.f; acc[1][i] = 0.f; }

    // Stage chunk c into buffer buf: 4 ops x 1 KB, each op = 8 full rows.
    auto stage = [&](int c, int buf) {
        #pragma unroll
        for (int i = 0; i < 4; ++i) {
            const float* g = xrow + (size_t)i * 8 * DDIM + c * 32;
            __builtin_amdgcn_global_load_lds((gu32*)g,
                (lu32*)&sm.As[buf][wid * 1024 + i * 256], 16, 0, 0);
        }
    };
    // B frags for 16-K step: [0]=bh nt0, [1]=bh nt1, [2]=bm nt0, [3]=bm nt1
    auto loadB = [&](int s, f16x8 (&B)[4]) {
        #pragma unroll
        for (int f = 0; f < 4; ++f)
            B[f] = *(const f16x8*)(wl + (size_t)(f >> 1) * WLVL
                                      + ((size_t)((s16b + s) * 2 + (f & 1)) << 9));
    };
    auto computeStep = [&](const float4* As4, int s, const f16x8 (&B)[4]) {
        const int g0 = s * 4 + hi * 2;
        float4 G0 = As4[(row << 3) + ( g0      ^ (row & 7))];  // swizzled read
        float4 G1 = As4[(row << 3) + ((g0 + 1) ^ (row & 7))];
        float av[8] = {G0.x, G0.y, G0.z, G0.w, G1.x, G1.y, G1.z, G1.w};
        f16x8 ah, am;
        #pragma unroll
        for (int j = 0; j < 8; ++j) {
            _Float16 h, m;
            split2(av[j] * XSCALE, h, m);
            ah[j] = h; am[j] = m;
        }
        #pragma unroll
        for (int nt = 0; nt < 2; ++nt) {
            acc[nt] = __builtin_amdgcn_mfma_f32_32x32x16_f16(ah, B[nt],     acc[nt], 0, 0, 0);
            acc[nt] = __builtin_amdgcn_mfma_f32_32x32x16_f16(am, B[nt],     acc[nt], 0, 0, 0);
            acc[nt] = __builtin_amdgcn_mfma_f32_32x32x16_f16(ah, B[2 + nt], acc[nt], 0, 0, 0);
            acc[nt] = __builtin_amdgcn_mfma_f32_32x32x16_f16(am, B[2 + nt], acc[nt], 0, 0, 0);
        }
    };

    f16x8 Bb[2][4];                  // step t lives in Bb[t&1]
    stage(0, 0);
    loadB(0, Bb[0]);
    __syncthreads();                 // vmcnt(0) drain: chunk 0 resident

    #pragma unroll
    for (int c = 0; c < NCH; ++c) {
        const int buf = c & 1;
        if (c + 1 < NCH) stage(c + 1, buf ^ 1);   // issue next chunk DMA
        const float4* As4 = (const float4*)&sm.As[buf][wid * 1024];
        // step 0 of chunk: prefetch B for step 1, pin, compute
        loadB(c * 2 + 1, Bb[1]);
        __builtin_amdgcn_sched_barrier(0);
        computeStep(As4, 0, Bb[0]);
        // step 1: prefetch B for next chunk's step 0, pin, compute
        if (c + 1 < NCH) loadB(c * 2 + 2, Bb[0]);
        __builtin_amdgcn_sched_barrier(0);
        computeStep(As4, 1, Bb[1]);
        __syncthreads();             // one drain/chunk: waits chunk c+1 DMA
    }

    // ---- epilogue (As dead; ep overlays it) ----
    // C/D: col(expert%32)=lane&31, row(token)=(reg&3)+8*(reg>>2)+4*(lane>>5).
    #pragma unroll
    for (int nt = 0; nt < 2; ++nt)
        #pragma unroll
        for (int r = 0; r < 16; ++r)
            sm.ep.pl[wid * 2 + nt][r][lane] = acc[nt][r];
    __syncthreads();

    // Combine 8 K-slices (fixed order), sigmoid, score store (coalesced).
    {
        const int tok = tid >> 4;               // 0..31
        const int e0  = (tid & 15) * 4;         // 0..60
        const int nt  = e0 >> 5;
        const int r   = (tok & 3) | ((tok >> 3) << 2);
        const int ln  = ((tok >> 2) & 1) * 32 + (e0 & 31);
        f32x4 s4 = {0.f, 0.f, 0.f, 0.f};
        #pragma unroll
        for (int w = 0; w < 8; ++w)
            s4 += *(const f32x4*)&sm.ep.pl[w * 2 + nt][r][ln];
        float4 sv;
        sv.x = 1.0f / (1.0f + expf(-s4[0] * LUNSCALE));
        sv.y = 1.0f / (1.0f + expf(-s4[1] * LUNSCALE));
        sv.z = 1.0f / (1.0f + expf(-s4[2] * LUNSCALE));
        sv.w = 1.0f / (1.0f + expf(-s4[3] * LUNSCALE));
        sm.ep.sct[e0 + 0][tok] = sv.x;
        sm.ep.sct[e0 + 1][tok] = sv.y;
        sm.ep.sct[e0 + 2][tok] = sv.z;
        sm.ep.sct[e0 + 3][tok] = sv.w;
        *(float4*)&out[OFF_SC + (size_t)(t0b + tok) * NE + e0] = sv;
    }
    __syncthreads();

    // Top-8: waves 0-1; lane = expert-group x 16 tokens.
    float entv = 0.f;
    if (wid < 2) {
        const int tl = wid * 16 + (lane & 15);
        const int eg = lane >> 4;               // expert group of 16
        float v[16];
        #pragma unroll
        for (int i = 0; i < 16; ++i)
            v[i] = sm.ep.sct[eg * 16 + i][tl] + sm.ep.bsh[eg * 16 + i];

        float ch[TK]; int ci[TK]; float ssum = 0.f;
        #pragma unroll
        for (int p = 0; p < TK; ++p) {
            float bv = v[0]; int bi = 0;
            #pragma unroll
            for (int i = 1; i < 16; ++i) {      // strict '>': lowest idx on tie
                const bool sgt = v[i] > bv;
                bv = sgt ? v[i] : bv;
                bi = sgt ? i : bi;
            }
            int be = eg * 16 + bi;
            {   // combine groups: lane^16 (same token, other group)
                float ov = __shfl_xor(bv, 16);
                int   oe = __shfl_xor(be, 16);
                const bool tk = (ov > bv) || (ov == bv && oe < be);
                bv = tk ? ov : bv; be = tk ? oe : be;
            }
            {   // lane^32
                float ov = __shfl_xor(bv, 32);
                int   oe = __shfl_xor(be, 32);
                const bool tk = (ov > bv) || (ov == bv && oe < be);
                bv = tk ? ov : bv; be = tk ? oe : be;
            }
            #pragma unroll
            for (int i = 0; i < 16; ++i)        // static-index mask (rule #20)
                v[i] = (be == eg * 16 + i) ? -1e30f : v[i];
            const float sc = sm.ep.sct[be][tl]; // unbiased score
            ch[p] = sc; ci[p] = be; ssum += sc;
        }
        if (eg == 0) {
            const float inv = 1.0f / (ssum + 1e-20f);
            #pragma unroll
            for (int p = 0; p < TK; ++p) {
                atomicAdd(&sm.ep.hist[ci[p]], 1);   // LDS atomic only
                const float pn = ch[p] * inv;   // ROUTE_SCALE == 1.0
                out[OFF_TOP + (size_t)(t0b + tl) * TK + p] = pn;
                out[OFF_IDX + (size_t)(t0b + tl) * TK + p] = (float)ci[p];
                entv += pn * logf(pn);
            }
        }
        entv += __shfl_down(entv, 8);
        entv += __shfl_down(entv, 4);
        entv += __shfl_down(entv, 2);
        entv += __shfl_down(entv, 1);
        if (lane == 0) sm.ep.entw[wid] = entv;
    }
    __syncthreads();

    // Per-block partials: plain coalesced stores, NO global atomics.
    if (tid == 0) entp[blockIdx.x] = sm.ep.entw[0] + sm.ep.entw[1];
    if (tid < NE) histc[blockIdx.x * NE + tid] = sm.ep.hist[tid];
}

// ---------------------------------------------------------------------------
// Finalize: reduce per-block histogram rows and entropy partials.
// ---------------------------------------------------------------------------
__global__ __launch_bounds__(256)
void finalize(const int* __restrict__ histc,
              const float* __restrict__ entp,
              float* __restrict__ out)
{
    __shared__ int   hred[4][NE];
    __shared__ float ered[256];
    const int tid = threadIdx.x;
    {
        const int e = tid & 63, p = tid >> 6;   // 4 partitions x 128 blocks
        int s = 0;
        for (int b = p * 128; b < p * 128 + 128; ++b)
            s += histc[b * NE + e];
        hred[p][e] = s;
    }
    float ev = 0.f;
    for (int i = tid; i < NBLK; i += 256) ev += entp[i];
    ered[tid] = ev;
    __syncthreads();
    if (tid < NE)
        out[OFF_HIST + tid] =
            (float)(hred[0][tid] + hred[1][tid] + hred[2][tid] + hred[3][tid]);
    #pragma unroll
    for (int o = 128; o > 0; o >>= 1) {
        if (tid < o) ered[tid] += ered[tid + o];
        __syncthreads();
    }
    if (tid == 0) out[OFF_ENT] = -ered[0] * (1.0f / (float)N_TOK);
}

extern "C" void kernel_launch(void* const* d_in, const int* in_sizes, int n_in,
                              void* d_out, int out_size, void* d_ws, size_t ws_size,
                              hipStream_t stream) {
    const float* x    = (const float*)d_in[0];   // [16384, 2048]
    const float* w    = (const float*)d_in[1];   // [64, 2048]
    const float* bias = (const float*)d_in[2];   // [64]
    float* out = (float*)d_out;
    unsigned short* wre = (unsigned short*)d_ws;            // 512 KB (2 levels)
    int*   histc = (int*)  ((char*)d_ws + HISTC_OFF);
    float* entp  = (float*)((char*)d_ws + ENTP_OFF);

    prep_w      <<<dim3(256),  dim3(64),  0, stream>>>(w, wre);
    router_fused<<<dim3(NBLK), dim3(512), 0, stream>>>(x, wre, bias, out,
                                                       histc, entp);
    finalize    <<<dim3(1),    dim3(256), 0, stream>>>(histc, entp, out);
}